// Round 14
// baseline (2708.036 us; speedup 1.0000x reference)
//
#include <hip/hip_runtime.h>
#include <stdint.h>

// KNN BC policy: B=1024 x D=512 queries vs N=100000 bank, top-16 L2, mean of acts [1024,32].
// R14 = R13 (fp8 e4m3, counted-vmcnt async, typed LDS reads, stride-5 mbuf, top-4/block)
// with BK 64->32: dbuf LDS drops 32->16.5 KB -> 8 blocks/CU = 32 waves/CU (HW max).
// 2x the latency-hiding waves for 2x the barriers -- occupancy was the decisive lever
// in every prior round. K-loop: 16 kt, 2 gloads/wave/kt, vmcnt(2), 8 ds_read_b64 + 8 MFMA.

#define NQ     1024
#define DIM    512
#define NB     100000
#define NPAD   100352          // 784 * 128
#define NBLK   784             // n-blocks of 128 rows
#define ADIM   32
#define KNB    16
#define NCAND  (NBLK * 4)      // 3136 candidates per query
#define WSPAN  (NCAND / 8)     // 392 per wave in topk

typedef __attribute__((ext_vector_type(16))) float f32x16;
typedef long long ll64;
typedef unsigned long long u64;

__device__ inline int   f2i(float f) { union { float f; int i; } u; u.f = f; return u.i; }
__device__ inline float i2f(int i)   { union { int i; float f; } u; u.i = i; return u.f; }

__device__ inline void gload16(const void* g, void* l) {
  __builtin_amdgcn_global_load_lds(
      (const __attribute__((address_space(1))) unsigned int*)g,
      (__attribute__((address_space(3))) unsigned int*)l, 16, 0, 0);
}

__device__ inline f32x16 mfma8(u64 a, u64 b, f32x16 c) {
  return __builtin_amdgcn_mfma_f32_32x32x16_fp8_fp8((ll64)a, (ll64)b, c, 0, 0, 0);
}

// ---------------- conversion (fp32 -> fp8 e4m3) + norms ----------------
__global__ __launch_bounds__(256) void convert_bank_kernel(
    const float* __restrict__ bank, unsigned char* __restrict__ bank8,
    float* __restrict__ b2) {
  const int row  = blockIdx.x * 4 + (threadIdx.x >> 6);
  const int lane = threadIdx.x & 63;
  if (row < NB) {
    const float* src = bank + (size_t)row * DIM + lane * 8;
    const float4 a = ((const float4*)src)[0];
    const float4 b = ((const float4*)src)[1];
    float ss = a.x*a.x + a.y*a.y + a.z*a.z + a.w*a.w
             + b.x*b.x + b.y*b.y + b.z*b.z + b.w*b.w;
    #pragma unroll
    for (int o = 32; o; o >>= 1) ss += __shfl_xor(ss, o);
    int w0 = __builtin_amdgcn_cvt_pk_fp8_f32(a.x, a.y, 0, false);
    w0     = __builtin_amdgcn_cvt_pk_fp8_f32(a.z, a.w, w0, true);
    int w1 = __builtin_amdgcn_cvt_pk_fp8_f32(b.x, b.y, 0, false);
    w1     = __builtin_amdgcn_cvt_pk_fp8_f32(b.z, b.w, w1, true);
    *(int2*)(bank8 + (size_t)row * DIM + lane * 8) = make_int2(w0, w1);
    if (lane == 0) b2[row] = ss;
  } else {
    *(int2*)(bank8 + (size_t)row * DIM + lane * 8) = make_int2(0, 0);
    if (lane == 0) b2[row] = 1e30f;   // pad rows never selected
  }
}

__global__ __launch_bounds__(256) void convert_obs_kernel(
    const float* __restrict__ obs, unsigned char* __restrict__ o8) {
  const int row  = blockIdx.x * 4 + (threadIdx.x >> 6);
  const int lane = threadIdx.x & 63;
  const float* src = obs + (size_t)row * DIM + lane * 8;
  const float4 a = ((const float4*)src)[0];
  const float4 b = ((const float4*)src)[1];
  int w0 = __builtin_amdgcn_cvt_pk_fp8_f32(a.x, a.y, 0, false);
  w0     = __builtin_amdgcn_cvt_pk_fp8_f32(a.z, a.w, w0, true);
  int w1 = __builtin_amdgcn_cvt_pk_fp8_f32(b.x, b.y, 0, false);
  w1     = __builtin_amdgcn_cvt_pk_fp8_f32(b.z, b.w, w1, true);
  *(int2*)(o8 + (size_t)row * DIM + lane * 8) = make_int2(w0, w1);
}

// ---------------- fp8 async-pipelined GEMM + in-register top-4 (BK=32) ----------------
// Block 256 thr = 4 waves (2wn x 2wq); wave = 64n x 64q (acc[2][2], 64 AGPR).
// BK=32 fp8 (16 K-steps). Per kt per wave: 2 gload_lds, 8 ds_read_b64, 8 MFMA.
// LDS: single u64 SH[2048] = 16 KB (A dbuf 0..1023, B dbuf 1024..2047) -> 8 blocks/CU.
__global__ __launch_bounds__(256, 8) void gemm_select_kernel(
    const unsigned char* __restrict__ A8g,  // bank fp8 [NPAD][512]
    const unsigned char* __restrict__ B8g,  // obs  fp8 [1024][512]
    const float* __restrict__ b2,
    float2* __restrict__ cand) {
  __shared__ u64  SH[2048];        // 16 KB: A[buf] = SH[buf*512+..], B[buf] = SH[1024+buf*512+..]
  __shared__ float b2s[128];

  const int tid = threadIdx.x;
  const int l   = tid & 63;
  const int w   = tid >> 6;
  const int wn  = w >> 1;
  const int wq  = w & 1;
  const int rl  = l & 31;
  const int kl  = l >> 5;

  // bijective XCD-chunk swizzle: 6272 = 8 x 784; q fast within chunk
  const int bid  = blockIdx.x;
  const int sb   = (bid & 7) * (NBLK * 8 / 8) + (bid >> 3);
  const int nblk = sb >> 3;
  const int qblk = sb & 7;
  const int n0   = nblk * 128;
  const int q0   = qblk * 128;

  if (tid < 128) b2s[tid] = b2[n0 + tid];

  f32x16 acc[2][2];
  #pragma unroll
  for (int i = 0; i < 2; ++i)
    #pragma unroll
    for (int j = 0; j < 2; ++j)
      #pragma unroll
      for (int r = 0; r < 16; ++r) acc[i][j][r] = 0.f;

  // staging: per kt, 128 rows x 32B per operand = 4KB = 1 gload/wave each.
  // dest linear (HW: base + l*16): row = w*32 + (l>>1), phys 16B-chunk = l&1.
  // source chunk inverse-swizzled: sc = (l&1) ^ ((row>>2)&1) = (l&1) ^ ((l>>3)&1).
  const int sr = l >> 1;
  const int sc = (l & 1) ^ ((l >> 3) & 1);
  const unsigned char* gA = A8g + (size_t)(n0 + w * 32 + sr) * DIM + sc * 16;
  const unsigned char* gB = B8g + (size_t)(q0 + w * 32 + sr) * DIM + sc * 16;

  auto STAGE = [&](int t) {
    const int buf = t & 1;
    const int k0  = t * 32;            // bytes along K
    gload16(gA + k0, &SH[buf * 512 + w * 128]);
    gload16(gB + k0, &SH[1024 + buf * 512 + w * 128]);
  };

  STAGE(0);
  STAGE(1);

  // fragment u64 indices; swizzle term (row>>2)&1 == (rl>>2)&1 for all four rows
  const int sw  = (rl >> 2) & 1;
  const int ia0 = (wn * 64 + rl) * 4 + kl;        // u64 units within A half
  const int ia1 = ia0 + 32 * 4;
  const int ib0 = 1024 + (wq * 64 + rl) * 4 + kl; // B half
  const int ib1 = ib0 + 32 * 4;

  #pragma unroll 1
  for (int t = 0; t < 15; ++t) {
    asm volatile("s_waitcnt vmcnt(2)" ::: "memory");   // t's 2 loads done; t+1's in flight
    __builtin_amdgcn_s_barrier();
    __builtin_amdgcn_sched_barrier(0);
    const int bo = (t & 1) * 512;
    #pragma unroll
    for (int ks = 0; ks < 2; ++ks) {
      const int co = (ks ^ sw) << 1;                   // u64 offset within row
      const u64 a0 = SH[bo + ia0 + co];
      const u64 a1 = SH[bo + ia1 + co];
      const u64 b0 = SH[bo + ib0 + co];
      const u64 b1 = SH[bo + ib1 + co];
      acc[0][0] = mfma8(a0, b0, acc[0][0]);
      acc[0][1] = mfma8(a0, b1, acc[0][1]);
      acc[1][0] = mfma8(a1, b0, acc[1][0]);
      acc[1][1] = mfma8(a1, b1, acc[1][1]);
    }
    __builtin_amdgcn_sched_barrier(0);
    __builtin_amdgcn_s_barrier();   // all reads of buf done -> safe to overwrite
    if (t < 14) STAGE(t + 2);
  }
  {
    asm volatile("s_waitcnt vmcnt(0)" ::: "memory");
    __builtin_amdgcn_s_barrier();
    __builtin_amdgcn_sched_barrier(0);
    const int bo = 512;               // t = 15 -> buf 1
    #pragma unroll
    for (int ks = 0; ks < 2; ++ks) {
      const int co = (ks ^ sw) << 1;
      const u64 a0 = SH[bo + ia0 + co];
      const u64 a1 = SH[bo + ia1 + co];
      const u64 b0 = SH[bo + ib0 + co];
      const u64 b1 = SH[bo + ib1 + co];
      acc[0][0] = mfma8(a0, b0, acc[0][0]);
      acc[0][1] = mfma8(a0, b1, acc[0][1]);
      acc[1][0] = mfma8(a1, b0, acc[1][0]);
      acc[1][1] = mfma8(a1, b1, acc[1][1]);
    }
    __builtin_amdgcn_sched_barrier(0);
    __builtin_amdgcn_s_barrier();
  }

  // ---- selection: per qs (two 32q groups), per-lane top-4 over 32 n-scores ----
  // mbuf rows stride-5 float2 (40B): spreads 32 lanes across 16 bank-pairs (R13 fix).
  float2* mbuf = (float2*)(&SH[0]);   // overlay: [8 lists][32 q] x stride 5 = 10 KB
  #pragma unroll
  for (int qs = 0; qs < 2; ++qs) {
    float ts[4]; int ti[4];
    #pragma unroll
    for (int i = 0; i < 4; ++i) { ts[i] = 1e38f; ti[i] = -1; }
    #pragma unroll
    for (int ns = 0; ns < 2; ++ns) {
      #pragma unroll
      for (int r = 0; r < 16; ++r) {
        const int nl = wn * 64 + ns * 32 + (r & 3) + 8 * (r >> 2) + 4 * kl;
        const float sc2 = fmaf(0.5f, b2s[nl], -acc[ns][qs][r]);
        if (sc2 < ts[3]) {
          float cs = sc2; int ci = n0 + nl;
          #pragma unroll
          for (int p = 0; p < 4; ++p) {
            if (cs < ts[p]) {
              float tf = ts[p]; ts[p] = cs; cs = tf;
              int   tt = ti[p]; ti[p] = ci; ci = tt;
            }
          }
        }
      }
    }
    // lane-pair (l^32) head-merge: top-4 of combined 8 -> mbuf
    float2* mrow = mbuf + ((((wn * 2 + wq) * 2 + qs) * 32) + rl) * 5;
    for (int k = 0; k < 4; ++k) {
      const float ov = __shfl_xor(ts[0], 32);
      const int   oi = __shfl_xor(ti[0], 32);
      const bool mine = (ts[0] < ov) || (ts[0] == ov && kl == 0);
      const float wv = mine ? ts[0] : ov;
      const int   wi = mine ? ti[0] : oi;
      if (mine) {
        #pragma unroll
        for (int p = 0; p < 3; ++p) { ts[p] = ts[p+1]; ti[p] = ti[p+1]; }
        ts[3] = 1e38f; ti[3] = -1;
      }
      if (kl == 0) mrow[k] = make_float2(wv, i2f(wi));
    }
  }
  __syncthreads();

  // ---- cross-wn merge (sorted 4+4 -> 4) + global store; 128 q-slots ----
  if (tid < 128) {
    const int wq_f = tid >> 6;
    const int qs_f = (tid >> 5) & 1;
    const int rl_f = tid & 31;
    const float2* pa = mbuf + ((((0 * 2 + wq_f) * 2 + qs_f) * 32) + rl_f) * 5;
    const float2* pb = mbuf + ((((1 * 2 + wq_f) * 2 + qs_f) * 32) + rl_f) * 5;
    float av[4], bv[4]; int ai[4], bi[4];
    #pragma unroll
    for (int j = 0; j < 4; ++j) {
      const float2 ta = pa[j]; av[j] = ta.x; ai[j] = f2i(ta.y);
      const float2 tb = pb[j]; bv[j] = tb.x; bi[j] = f2i(tb.y);
    }
    const int q = q0 + wq_f * 64 + qs_f * 32 + rl_f;
    float2* outp = cand + ((size_t)q * NBLK + nblk) * 4;
    for (int k = 0; k < 4; ++k) {
      const bool ta = (av[0] <= bv[0]);
      outp[k] = make_float2(ta ? av[0] : bv[0], i2f(ta ? ai[0] : bi[0]));
      if (ta) {
        #pragma unroll
        for (int p = 0; p < 3; ++p) { av[p] = av[p+1]; ai[p] = ai[p+1]; }
        av[3] = 1e38f;
      } else {
        #pragma unroll
        for (int p = 0; p < 3; ++p) { bv[p] = bv[p+1]; bi[p] = bi[p+1]; }
        bv[3] = 1e38f;
      }
    }
  }
}

// ---------------- per-query merge + exact rerank (512 thr, direct-global scan) ----------------
__global__ __launch_bounds__(512) void topk_kernel(
    const float2* __restrict__ cand, const float* __restrict__ obs,
    const float* __restrict__ bank, const float* __restrict__ acts,
    float* __restrict__ out) {
  __shared__ float2 wtop[256];       // 8 waves x 32
  __shared__ int   selidx[32];
  __shared__ float exd[32];
  __shared__ int   sel2[16];
  const int q    = blockIdx.x;
  const int tid  = threadIdx.x;
  const int lane = tid & 63;
  const int w    = tid >> 6;         // 0..7

  // per-lane list over this wave's 392-entry span: each lane sees <=7 entries,
  // so a 7-deep sorted list is EXACT (wave extraction = exact wave top-32).
  const float2* src = cand + (size_t)q * NCAND + (size_t)w * WSPAN;
  float ts[7]; int ti[7];
  #pragma unroll
  for (int i = 0; i < 7; ++i) { ts[i] = 1e38f; ti[i] = -1; }
  for (int i = lane; i < WSPAN; i += 64) {
    const float2 e = src[i];
    const float s = e.x;
    if (s < ts[6]) {
      float cs = s; int ci = f2i(e.y);
      #pragma unroll
      for (int pp = 0; pp < 7; ++pp) {
        if (cs < ts[pp]) {
          float tf = ts[pp]; ts[pp] = cs; cs = tf;
          int   tt = ti[pp]; ti[pp] = ci; ci = tt;
        }
      }
    }
  }
  // 32 head-extractions per wave -> wtop[w*32 + k]
  for (int k = 0; k < 32; ++k) {
    float bv = ts[0]; int bi = ti[0]; int bl = lane;
    #pragma unroll
    for (int o = 32; o; o >>= 1) {
      float ov = __shfl_xor(bv, o); int oi = __shfl_xor(bi, o); int ol = __shfl_xor(bl, o);
      if (ov < bv || (ov == bv && ol < bl)) { bv = ov; bi = oi; bl = ol; }
    }
    if (lane == bl) {
      #pragma unroll
      for (int pp = 0; pp < 6; ++pp) { ts[pp] = ts[pp+1]; ti[pp] = ti[pp+1]; }
      ts[6] = 1e38f; ti[6] = -1;
    }
    if (lane == 0) wtop[w * 32 + k] = make_float2(bv, i2f(bi));
  }
  __syncthreads();

  // wave 0: 256 wave-winners -> top-32. 4 entries/lane, locally sorted, head-merge.
  if (w == 0) {
    float rv[4]; int ri[4];
    #pragma unroll
    for (int j = 0; j < 4; ++j) {
      const float2 e = wtop[j * 64 + lane];
      rv[j] = e.x; ri[j] = f2i(e.y);
    }
    #pragma unroll
    for (int a = 1; a < 4; ++a) {
      #pragma unroll
      for (int b2_ = 4 - 1; b2_ >= 1; --b2_) {
        if (rv[b2_] < rv[b2_ - 1]) {
          float tf = rv[b2_]; rv[b2_] = rv[b2_ - 1]; rv[b2_ - 1] = tf;
          int   tt = ri[b2_]; ri[b2_] = ri[b2_ - 1]; ri[b2_ - 1] = tt;
        }
      }
    }
    for (int k = 0; k < 32; ++k) {
      float bv = rv[0]; int bi = ri[0]; int bl = lane;
      #pragma unroll
      for (int o = 32; o; o >>= 1) {
        float ov = __shfl_xor(bv, o); int oi = __shfl_xor(bi, o); int ol = __shfl_xor(bl, o);
        if (ov < bv || (ov == bv && ol < bl)) { bv = ov; bi = oi; bl = ol; }
      }
      if (lane == bl) {
        #pragma unroll
        for (int pp = 0; pp < 3; ++pp) { rv[pp] = rv[pp+1]; ri[pp] = ri[pp+1]; }
        rv[3] = 1e38f; ri[3] = -1;
      }
      if (lane == 0) selidx[k] = bi;
    }
  }
  __syncthreads();

  // exact fp32 distances for the 32 candidates (8 waves, 4 each)
  const float* qp = obs + (size_t)q * DIM + lane * 8;
  const float4 qa = ((const float4*)qp)[0];
  const float4 qb = ((const float4*)qp)[1];
  for (int c2 = w; c2 < 32; c2 += 8) {
    const int idx = selidx[c2];
    const float* bp_ = bank + (size_t)idx * DIM + lane * 8;
    const float4 ba = ((const float4*)bp_)[0];
    const float4 bb = ((const float4*)bp_)[1];
    const float d0 = qa.x-ba.x, d1 = qa.y-ba.y, d2 = qa.z-ba.z, d3 = qa.w-ba.w;
    const float d4 = qb.x-bb.x, d5 = qb.y-bb.y, d6 = qb.z-bb.z, d7 = qb.w-bb.w;
    float ss = d0*d0 + d1*d1 + d2*d2 + d3*d3 + d4*d4 + d5*d5 + d6*d6 + d7*d7;
    #pragma unroll
    for (int o = 32; o; o >>= 1) ss += __shfl_xor(ss, o);
    if (lane == 0) exd[c2] = ss;
  }
  __syncthreads();

  // exact top-16 of 32
  if (w == 0) {
    const float v  = (lane < 32) ? exd[lane] : 1e38f;
    const int   id = (lane < 32) ? selidx[lane] : -1;
    float lastv = -1e38f; int lastp = -1;
    for (int k = 0; k < 16; ++k) {
      float bv = 1e38f; int bi = -1; int bp = 64;
      const bool gt = (v > lastv) || (v == lastv && lane > lastp);
      if (gt) { bv = v; bi = id; bp = lane; }
      #pragma unroll
      for (int o = 32; o; o >>= 1) {
        float ov = __shfl_xor(bv, o); int oi = __shfl_xor(bi, o); int op = __shfl_xor(bp, o);
        if (ov < bv || (ov == bv && op < bp)) { bv = ov; bi = oi; bp = op; }
      }
      if (lane == 0) sel2[k] = bi;
      lastv = bv; lastp = bp;
    }
  }
  __syncthreads();

  if (tid < ADIM) {
    float s = 0.f;
    #pragma unroll
    for (int t2 = 0; t2 < KNB; ++t2) s += acts[(size_t)sel2[t2] * ADIM + tid];
    out[(size_t)q * ADIM + tid] = s * (1.0f / KNB);
  }
}

// ---------------- host launch ----------------
extern "C" void kernel_launch(void* const* d_in, const int* in_sizes, int n_in,
                              void* d_out, int out_size, void* d_ws, size_t ws_size,
                              hipStream_t stream) {
  const float* obs  = (const float*)d_in[0];
  const float* bank = (const float*)d_in[1];
  const float* acts = (const float*)d_in[2];
  float* out = (float*)d_out;
  char* ws = (char*)d_ws;

  size_t off = 0;
  auto take = [&](size_t b) { size_t o = off; off += (b + 255) & ~(size_t)255; return o; };
  const size_t off_b8   = take((size_t)NPAD * DIM);              // 51.4 MB
  const size_t off_o8   = take((size_t)NQ * DIM);                // 0.5 MB
  const size_t off_b2   = take((size_t)NPAD * 4);                // 0.4 MB
  const size_t off_cand = take((size_t)NQ * NCAND * 8);          // 25.7 MB

  unsigned char* bank8 = (unsigned char*)(ws + off_b8);
  unsigned char* obs8  = (unsigned char*)(ws + off_o8);
  float*  b2   = (float*)(ws + off_b2);
  float2* cand = (float2*)(ws + off_cand);

  convert_bank_kernel<<<NPAD / 4, 256, 0, stream>>>(bank, bank8, b2);
  convert_obs_kernel<<<NQ / 4, 256, 0, stream>>>(obs, obs8);
  gemm_select_kernel<<<NBLK * 8, 256, 0, stream>>>(bank8, obs8, b2, cand);
  topk_kernel<<<NQ, 512, 0, stream>>>(cand, obs, bank, acts, out);
}

// Round 15
// 215.809 us; speedup vs baseline: 12.5483x; 12.5483x over previous
//
#include <hip/hip_runtime.h>
#include <stdint.h>

// KNN BC policy: B=1024 x D=512 queries vs N=100000 bank, top-16 L2, mean of acts [1024,32].
// R15: gemm reverted verbatim to R13 (best: 141us; fp8 e4m3, BK=64, counted-vmcnt async,
// typed LDS reads, stride-5 mbuf, top-4/block). R14 lesson: launch_bounds(256,8) forced
// 64-reg budget -> acc spilled to scratch (10GB traffic). Register-bound at 4 waves/SIMD.
// topk restructured: per-wave top-12 (12 extractions) -> 96 cands, rerank ALL 96 exactly
// (no top-32 narrowing phase), final top-16-of-96. Serial shfl-chain 80 -> 28 extractions.

#define NQ     1024
#define DIM    512
#define NB     100000
#define NPAD   100352          // 784 * 128
#define NBLK   784             // n-blocks of 128 rows
#define ADIM   32
#define KNB    16
#define NCAND  (NBLK * 4)      // 3136 candidates per query
#define WSPAN  (NCAND / 8)     // 392 per wave in topk

typedef __attribute__((ext_vector_type(16))) float f32x16;
typedef long long ll64;
typedef unsigned long long u64;

__device__ inline int   f2i(float f) { union { float f; int i; } u; u.f = f; return u.i; }
__device__ inline float i2f(int i)   { union { int i; float f; } u; u.i = i; return u.f; }

__device__ inline void gload16(const void* g, void* l) {
  __builtin_amdgcn_global_load_lds(
      (const __attribute__((address_space(1))) unsigned int*)g,
      (__attribute__((address_space(3))) unsigned int*)l, 16, 0, 0);
}

__device__ inline f32x16 mfma8(u64 a, u64 b, f32x16 c) {
  return __builtin_amdgcn_mfma_f32_32x32x16_fp8_fp8((ll64)a, (ll64)b, c, 0, 0, 0);
}

// ---------------- conversion (fp32 -> fp8 e4m3) + norms ----------------
__global__ __launch_bounds__(256) void convert_bank_kernel(
    const float* __restrict__ bank, unsigned char* __restrict__ bank8,
    float* __restrict__ b2) {
  const int row  = blockIdx.x * 4 + (threadIdx.x >> 6);
  const int lane = threadIdx.x & 63;
  if (row < NB) {
    const float* src = bank + (size_t)row * DIM + lane * 8;
    const float4 a = ((const float4*)src)[0];
    const float4 b = ((const float4*)src)[1];
    float ss = a.x*a.x + a.y*a.y + a.z*a.z + a.w*a.w
             + b.x*b.x + b.y*b.y + b.z*b.z + b.w*b.w;
    #pragma unroll
    for (int o = 32; o; o >>= 1) ss += __shfl_xor(ss, o);
    int w0 = __builtin_amdgcn_cvt_pk_fp8_f32(a.x, a.y, 0, false);
    w0     = __builtin_amdgcn_cvt_pk_fp8_f32(a.z, a.w, w0, true);
    int w1 = __builtin_amdgcn_cvt_pk_fp8_f32(b.x, b.y, 0, false);
    w1     = __builtin_amdgcn_cvt_pk_fp8_f32(b.z, b.w, w1, true);
    *(int2*)(bank8 + (size_t)row * DIM + lane * 8) = make_int2(w0, w1);
    if (lane == 0) b2[row] = ss;
  } else {
    *(int2*)(bank8 + (size_t)row * DIM + lane * 8) = make_int2(0, 0);
    if (lane == 0) b2[row] = 1e30f;   // pad rows never selected
  }
}

__global__ __launch_bounds__(256) void convert_obs_kernel(
    const float* __restrict__ obs, unsigned char* __restrict__ o8) {
  const int row  = blockIdx.x * 4 + (threadIdx.x >> 6);
  const int lane = threadIdx.x & 63;
  const float* src = obs + (size_t)row * DIM + lane * 8;
  const float4 a = ((const float4*)src)[0];
  const float4 b = ((const float4*)src)[1];
  int w0 = __builtin_amdgcn_cvt_pk_fp8_f32(a.x, a.y, 0, false);
  w0     = __builtin_amdgcn_cvt_pk_fp8_f32(a.z, a.w, w0, true);
  int w1 = __builtin_amdgcn_cvt_pk_fp8_f32(b.x, b.y, 0, false);
  w1     = __builtin_amdgcn_cvt_pk_fp8_f32(b.z, b.w, w1, true);
  *(int2*)(o8 + (size_t)row * DIM + lane * 8) = make_int2(w0, w1);
}

// ---------------- fp8 async-pipelined GEMM + in-register top-4 (R13 verbatim) ----------------
__global__ __launch_bounds__(256, 4) void gemm_select_kernel(
    const unsigned char* __restrict__ A8g,  // bank fp8 [NPAD][512]
    const unsigned char* __restrict__ B8g,  // obs  fp8 [1024][512]
    const float* __restrict__ b2,
    float2* __restrict__ cand) {
  __shared__ u64  As64[2][1024];   // 2 x 8 KB: [buf][row*8 + u64slot]
  __shared__ u64  Bs64[2][1024];   // 2 x 8 KB
  __shared__ float b2s[128];

  const int tid = threadIdx.x;
  const int l   = tid & 63;
  const int w   = tid >> 6;
  const int wn  = w >> 1;
  const int wq  = w & 1;
  const int rl  = l & 31;
  const int kl  = l >> 5;

  // bijective XCD-chunk swizzle: 6272 = 8 x 784; q fast within chunk
  const int bid  = blockIdx.x;
  const int sb   = (bid & 7) * (NBLK * 8 / 8) + (bid >> 3);
  const int nblk = sb >> 3;
  const int qblk = sb & 7;
  const int n0   = nblk * 128;
  const int q0   = qblk * 128;

  if (tid < 128) b2s[tid] = b2[n0 + tid];

  f32x16 acc[2][2];
  #pragma unroll
  for (int i = 0; i < 2; ++i)
    #pragma unroll
    for (int j = 0; j < 2; ++j)
      #pragma unroll
      for (int r = 0; r < 16; ++r) acc[i][j][r] = 0.f;

  const int sr = l >> 2;
  const int sc = (l & 3) ^ ((l >> 3) & 3);
  const unsigned char* gA0 = A8g + (size_t)(n0 + (2 * w) * 16 + sr) * DIM + sc * 16;
  const unsigned char* gA1 = gA0 + (size_t)16 * DIM;
  const unsigned char* gB0 = B8g + (size_t)(q0 + (2 * w) * 16 + sr) * DIM + sc * 16;
  const unsigned char* gB1 = gB0 + (size_t)16 * DIM;

  auto STAGE = [&](int t) {
    const int buf = t & 1;
    const int k0  = t * 64;            // bytes along K
    gload16(gA0 + k0, &As64[buf][(2 * w) * 128]);
    gload16(gA1 + k0, &As64[buf][(2 * w) * 128 + 128]);
    gload16(gB0 + k0, &Bs64[buf][(2 * w) * 128]);
    gload16(gB1 + k0, &Bs64[buf][(2 * w) * 128 + 128]);
  };

  STAGE(0);
  STAGE(1);

  const int sw  = (rl >> 1) & 3;
  const int ia0 = (wn * 64 + rl) * 8 + kl;        // u64 units
  const int ia1 = ia0 + 32 * 8;
  const int ib0 = (wq * 64 + rl) * 8 + kl;
  const int ib1 = ib0 + 32 * 8;

  #pragma unroll 1
  for (int t = 0; t < 7; ++t) {
    asm volatile("s_waitcnt vmcnt(4)" ::: "memory");   // t's loads done; t+1's in flight
    __builtin_amdgcn_s_barrier();
    __builtin_amdgcn_sched_barrier(0);
    const int buf = t & 1;
    #pragma unroll
    for (int ks = 0; ks < 4; ++ks) {
      const int co = (ks ^ sw) << 1;                   // u64 offset within row
      const u64 a0 = As64[buf][ia0 + co];
      const u64 a1 = As64[buf][ia1 + co];
      const u64 b0 = Bs64[buf][ib0 + co];
      const u64 b1 = Bs64[buf][ib1 + co];
      acc[0][0] = mfma8(a0, b0, acc[0][0]);
      acc[0][1] = mfma8(a0, b1, acc[0][1]);
      acc[1][0] = mfma8(a1, b0, acc[1][0]);
      acc[1][1] = mfma8(a1, b1, acc[1][1]);
    }
    __builtin_amdgcn_sched_barrier(0);
    __builtin_amdgcn_s_barrier();   // all reads of buf done -> safe to overwrite
    if (t < 6) STAGE(t + 2);
  }
  {
    asm volatile("s_waitcnt vmcnt(0)" ::: "memory");
    __builtin_amdgcn_s_barrier();
    __builtin_amdgcn_sched_barrier(0);
    #pragma unroll
    for (int ks = 0; ks < 4; ++ks) {
      const int co = (ks ^ sw) << 1;
      const u64 a0 = As64[1][ia0 + co];
      const u64 a1 = As64[1][ia1 + co];
      const u64 b0 = Bs64[1][ib0 + co];
      const u64 b1 = Bs64[1][ib1 + co];
      acc[0][0] = mfma8(a0, b0, acc[0][0]);
      acc[0][1] = mfma8(a0, b1, acc[0][1]);
      acc[1][0] = mfma8(a1, b0, acc[1][0]);
      acc[1][1] = mfma8(a1, b1, acc[1][1]);
    }
    __builtin_amdgcn_sched_barrier(0);
    __builtin_amdgcn_s_barrier();
  }

  // ---- selection: per qs (two 32q groups), per-lane top-4 over 32 n-scores ----
  float2* mbuf = (float2*)(&As64[0][0]);   // overlay: [8 lists][32 q] x stride 5 = 10 KB
  #pragma unroll
  for (int qs = 0; qs < 2; ++qs) {
    float ts[4]; int ti[4];
    #pragma unroll
    for (int i = 0; i < 4; ++i) { ts[i] = 1e38f; ti[i] = -1; }
    #pragma unroll
    for (int ns = 0; ns < 2; ++ns) {
      #pragma unroll
      for (int r = 0; r < 16; ++r) {
        const int nl = wn * 64 + ns * 32 + (r & 3) + 8 * (r >> 2) + 4 * kl;
        const float sc2 = fmaf(0.5f, b2s[nl], -acc[ns][qs][r]);
        if (sc2 < ts[3]) {
          float cs = sc2; int ci = n0 + nl;
          #pragma unroll
          for (int p = 0; p < 4; ++p) {
            if (cs < ts[p]) {
              float tf = ts[p]; ts[p] = cs; cs = tf;
              int   tt = ti[p]; ti[p] = ci; ci = tt;
            }
          }
        }
      }
    }
    // lane-pair (l^32) head-merge: top-4 of combined 8 -> mbuf (stride-5 rows, R13 fix)
    float2* mrow = mbuf + ((((wn * 2 + wq) * 2 + qs) * 32) + rl) * 5;
    for (int k = 0; k < 4; ++k) {
      const float ov = __shfl_xor(ts[0], 32);
      const int   oi = __shfl_xor(ti[0], 32);
      const bool mine = (ts[0] < ov) || (ts[0] == ov && kl == 0);
      const float wv = mine ? ts[0] : ov;
      const int   wi = mine ? ti[0] : oi;
      if (mine) {
        #pragma unroll
        for (int p = 0; p < 3; ++p) { ts[p] = ts[p+1]; ti[p] = ti[p+1]; }
        ts[3] = 1e38f; ti[3] = -1;
      }
      if (kl == 0) mrow[k] = make_float2(wv, i2f(wi));
    }
  }
  __syncthreads();

  // ---- cross-wn merge (sorted 4+4 -> 4) + global store; 128 q-slots ----
  if (tid < 128) {
    const int wq_f = tid >> 6;
    const int qs_f = (tid >> 5) & 1;
    const int rl_f = tid & 31;
    const float2* pa = mbuf + ((((0 * 2 + wq_f) * 2 + qs_f) * 32) + rl_f) * 5;
    const float2* pb = mbuf + ((((1 * 2 + wq_f) * 2 + qs_f) * 32) + rl_f) * 5;
    float av[4], bv[4]; int ai[4], bi[4];
    #pragma unroll
    for (int j = 0; j < 4; ++j) {
      const float2 ta = pa[j]; av[j] = ta.x; ai[j] = f2i(ta.y);
      const float2 tb = pb[j]; bv[j] = tb.x; bi[j] = f2i(tb.y);
    }
    const int q = q0 + wq_f * 64 + qs_f * 32 + rl_f;
    float2* outp = cand + ((size_t)q * NBLK + nblk) * 4;
    for (int k = 0; k < 4; ++k) {
      const bool ta = (av[0] <= bv[0]);
      outp[k] = make_float2(ta ? av[0] : bv[0], i2f(ta ? ai[0] : bi[0]));
      if (ta) {
        #pragma unroll
        for (int p = 0; p < 3; ++p) { av[p] = av[p+1]; ai[p] = ai[p+1]; }
        av[3] = 1e38f;
      } else {
        #pragma unroll
        for (int p = 0; p < 3; ++p) { bv[p] = bv[p+1]; bi[p] = bi[p+1]; }
        bv[3] = 1e38f;
      }
    }
  }
}

// ---------------- per-query merge + exact rerank (512 thr) ----------------
// Per-wave top-12 (exact within wave) -> 96 candidates -> exact fp32 distance for all
// 96 -> exact top-16 of 96. Serial extraction chain: 12 + 16 (was 32+32+16).
__global__ __launch_bounds__(512) void topk_kernel(
    const float2* __restrict__ cand, const float* __restrict__ obs,
    const float* __restrict__ bank, const float* __restrict__ acts,
    float* __restrict__ out) {
  __shared__ float2 wtop[96];        // 8 waves x 12 (score, idx)
  __shared__ float  exd[96];
  __shared__ int    sel2[16];
  const int q    = blockIdx.x;
  const int tid  = threadIdx.x;
  const int lane = tid & 63;
  const int w    = tid >> 6;         // 0..7

  // per-lane list over this wave's 392-entry span: each lane sees <=7 entries,
  // so a 7-deep sorted list is EXACT (wave extraction = exact wave top-12).
  const float2* src = cand + (size_t)q * NCAND + (size_t)w * WSPAN;
  float ts[7]; int ti[7];
  #pragma unroll
  for (int i = 0; i < 7; ++i) { ts[i] = 1e38f; ti[i] = -1; }
  for (int i = lane; i < WSPAN; i += 64) {
    const float2 e = src[i];
    const float s = e.x;
    if (s < ts[6]) {
      float cs = s; int ci = f2i(e.y);
      #pragma unroll
      for (int pp = 0; pp < 7; ++pp) {
        if (cs < ts[pp]) {
          float tf = ts[pp]; ts[pp] = cs; cs = tf;
          int   tt = ti[pp]; ti[pp] = ci; ci = tt;
        }
      }
    }
  }
  // 12 head-extractions per wave -> wtop[w*12 + k]
  // (true top-16 membership: P(>=13 of 16 in one eighth) ~ 7e-10/query -> safe)
  for (int k = 0; k < 12; ++k) {
    float bv = ts[0]; int bi = ti[0]; int bl = lane;
    #pragma unroll
    for (int o = 32; o; o >>= 1) {
      float ov = __shfl_xor(bv, o); int oi = __shfl_xor(bi, o); int ol = __shfl_xor(bl, o);
      if (ov < bv || (ov == bv && ol < bl)) { bv = ov; bi = oi; bl = ol; }
    }
    if (lane == bl) {
      #pragma unroll
      for (int pp = 0; pp < 6; ++pp) { ts[pp] = ts[pp+1]; ti[pp] = ti[pp+1]; }
      ts[6] = 1e38f; ti[6] = -1;
    }
    if (lane == 0) wtop[w * 12 + k] = make_float2(bv, i2f(bi));
  }
  __syncthreads();

  // exact fp32 distances for all 96 candidates (8 waves, 12 each, unrolled)
  const float* qp = obs + (size_t)q * DIM + lane * 8;
  const float4 qa = ((const float4*)qp)[0];
  const float4 qb = ((const float4*)qp)[1];
  #pragma unroll
  for (int c2 = 0; c2 < 12; ++c2) {
    const int slot = w * 12 + c2;
    const int idx  = f2i(wtop[slot].y);
    const float* bp_ = bank + (size_t)idx * DIM + lane * 8;
    const float4 ba = ((const float4*)bp_)[0];
    const float4 bb = ((const float4*)bp_)[1];
    const float d0 = qa.x-ba.x, d1 = qa.y-ba.y, d2 = qa.z-ba.z, d3 = qa.w-ba.w;
    const float d4 = qb.x-bb.x, d5 = qb.y-bb.y, d6 = qb.z-bb.z, d7 = qb.w-bb.w;
    float ss = d0*d0 + d1*d1 + d2*d2 + d3*d3 + d4*d4 + d5*d5 + d6*d6 + d7*d7;
    #pragma unroll
    for (int o = 32; o; o >>= 1) ss += __shfl_xor(ss, o);
    if (lane == 0) exd[slot] = ss;
  }
  __syncthreads();

  // wave 0: exact top-16 of 96 (2 entries/lane for lanes<32, 1 else; index tie-break)
  if (w == 0) {
    float rv[2]; int ri[2];
    rv[0] = exd[lane];
    ri[0] = f2i(wtop[lane].y);
    if (lane < 32) { rv[1] = exd[64 + lane]; ri[1] = f2i(wtop[64 + lane].y); }
    else           { rv[1] = 1e38f;          ri[1] = 0x7fffffff; }
    if (rv[1] < rv[0] || (rv[1] == rv[0] && ri[1] < ri[0])) {
      float tf = rv[0]; rv[0] = rv[1]; rv[1] = tf;
      int   tt = ri[0]; ri[0] = ri[1]; ri[1] = tt;
    }
    for (int k = 0; k < 16; ++k) {
      float bv = rv[0]; int bi = ri[0]; int bl = lane;
      #pragma unroll
      for (int o = 32; o; o >>= 1) {
        float ov = __shfl_xor(bv, o); int oi = __shfl_xor(bi, o); int ol = __shfl_xor(bl, o);
        if (ov < bv || (ov == bv && oi < bi)) { bv = ov; bi = oi; bl = ol; }
      }
      if (lane == bl && bi == ri[0]) {
        rv[0] = rv[1]; ri[0] = ri[1];
        rv[1] = 1e38f; ri[1] = 0x7fffffff;
      }
      if (lane == 0) sel2[k] = bi;
    }
  }
  __syncthreads();

  if (tid < ADIM) {
    float s = 0.f;
    #pragma unroll
    for (int t2 = 0; t2 < KNB; ++t2) s += acts[(size_t)sel2[t2] * ADIM + tid];
    out[(size_t)q * ADIM + tid] = s * (1.0f / KNB);
  }
}

// ---------------- host launch ----------------
extern "C" void kernel_launch(void* const* d_in, const int* in_sizes, int n_in,
                              void* d_out, int out_size, void* d_ws, size_t ws_size,
                              hipStream_t stream) {
  const float* obs  = (const float*)d_in[0];
  const float* bank = (const float*)d_in[1];
  const float* acts = (const float*)d_in[2];
  float* out = (float*)d_out;
  char* ws = (char*)d_ws;

  size_t off = 0;
  auto take = [&](size_t b) { size_t o = off; off += (b + 255) & ~(size_t)255; return o; };
  const size_t off_b8   = take((size_t)NPAD * DIM);              // 51.4 MB
  const size_t off_o8   = take((size_t)NQ * DIM);                // 0.5 MB
  const size_t off_b2   = take((size_t)NPAD * 4);                // 0.4 MB
  const size_t off_cand = take((size_t)NQ * NCAND * 8);          // 25.7 MB

  unsigned char* bank8 = (unsigned char*)(ws + off_b8);
  unsigned char* obs8  = (unsigned char*)(ws + off_o8);
  float*  b2   = (float*)(ws + off_b2);
  float2* cand = (float2*)(ws + off_cand);

  convert_bank_kernel<<<NPAD / 4, 256, 0, stream>>>(bank, bank8, b2);
  convert_obs_kernel<<<NQ / 4, 256, 0, stream>>>(obs, obs8);
  gemm_select_kernel<<<NBLK * 8, 256, 0, stream>>>(bank8, obs8, b2, cand);
  topk_kernel<<<NQ, 512, 0, stream>>>(cand, obs, bank, acts, out);
}